// Round 4
// baseline (164.462 us; speedup 1.0000x reference)
//
#include <hip/hip_runtime.h>
#include <stdint.h>

#define KK 1000
#define NN 1000
#define MM 900000
#define FF 7
#define SENTINEL -9999.0f

typedef _Float16 h2v __attribute__((ext_vector_type(2)));
typedef __fp16  h2f __attribute__((ext_vector_type(2)));   // builtin return type

// Compile-time unroller: every loop index reaches the body as a constant
// expression after inlining, so activation arrays decompose into named
// scalars (SROA). Plain `#pragma unroll` left them runtime-indexed at SROA
// time -> scratch spill.
template <int N, typename F>
__device__ __forceinline__ void unroll_loop(F&& f) {
    if constexpr (N > 0) {
        unroll_loop<N - 1>(static_cast<F&&>(f));
        f(N - 1);
    }
}

// v_dot2_f32_f16: 2 f16 MACs + f32 accumulate in ONE VALU instruction.
#if __has_builtin(__builtin_amdgcn_fdot2)
__device__ __forceinline__ float dot2(h2v a, h2v b, float c) {
    return __builtin_amdgcn_fdot2(__builtin_bit_cast(h2f, a),
                                  __builtin_bit_cast(h2f, b), c, false);
}
#else
__device__ __forceinline__ float dot2(h2v a, h2v b, float c) {
    return fmaf((float)a.x, (float)b.x, fmaf((float)a.y, (float)b.y, c));
}
#endif

__device__ __forceinline__ h2v pkrtz(float a, float b) {
#if __has_builtin(__builtin_amdgcn_cvt_pkrtz)
    return __builtin_bit_cast(h2v, __builtin_amdgcn_cvt_pkrtz(a, b));
#else
    return h2v{(_Float16)a, (_Float16)b};
#endif
}

// ---------------- prep: zero grid + col sentinels + pack weights ------------
// One kernel instead of three launch slots: disjoint block ranges do disjoint
// jobs (no intra-kernel ordering needed; everything completes at kernel end).
// R0->R3 data says per-launch overhead here is ~10-15us, so launches are the
// target, not the (tiny, L3-resident) work itself.
#define ZB ((KK * NN / 2 + 255) / 256)          // 1954 blocks zero the grid
#define SB 4                                     // 4 blocks write col sentinels

__global__ __launch_bounds__(256) void prep(
    ulonglong2* __restrict__ g, float* __restrict__ outcol,
    const float* __restrict__ w2, const float* __restrict__ w3,
    h2v* __restrict__ w2h, h2v* __restrict__ w3h)
{
    int b = blockIdx.x;
    if (b < ZB) {
        int i = b * 256 + threadIdx.x;
        if (i < KK * NN / 2) g[i] = make_ulonglong2(0ULL, 0ULL);
    } else if (b < ZB + SB) {
        int i = (b - ZB) * 256 + threadIdx.x;
        if (i < NN) outcol[i] = SENTINEL;
    } else {
        int t = threadIdx.x;
        for (int p = t; p < 36 * 9; p += 256) {          // w2: 36x18 -> [36][9]
            int o = p / 9, ip = p - o * 9;
            w2h[p] = h2v{(_Float16)w2[o * 18 + 2 * ip],
                         (_Float16)w2[o * 18 + 2 * ip + 1]};
        }
        for (int p = t; p < 36 * 18; p += 256) {         // w3: 36x36 -> [36][18]
            int o = p / 18, ip = p - o * 18;
            w3h[p] = h2v{(_Float16)w3[o * 36 + 2 * ip],
                         (_Float16)w3[o * 36 + 2 * ip + 1]};
        }
    }
}

// ---------------- MLP + last-write-wins scatter, P=2 x f16 ------------------
// P=2 retry: R1's "P=2 neutral" was a spill artifact (240 regs vs 168 cap).
// With f16 activations the P=2 live set is ~70 regs -> fits the 128 cap at
// (256,4). Same uniform s_load bytes per wave now feed 2x the dot2 work:
// the correlated scalar-fetch stall fraction should halve.
__global__ __launch_bounds__(256, 4) void mlp_scatter(
    const float* __restrict__ in,    // [F][M]
    const int*   __restrict__ idx,   // [2][M]
    const float* __restrict__ w1, const float* __restrict__ b1,   // 18x7, 18
    const h2v*   __restrict__ w2h, const float* __restrict__ b2,  // [36][9], 36
    const h2v*   __restrict__ w3h, const float* __restrict__ b3,  // [36][18], 36
    const float* __restrict__ w4, const float* __restrict__ b4,   // 1x36, 1
    unsigned long long* __restrict__ grid)                        // K*N packed
{
    int t = blockIdx.x * 256 + threadIdx.x;
    int m0 = t * 2;                       // adjacent pair -> float2/int2 loads
    if (m0 >= MM) return;

    float2 x[FF];
    unroll_loop<FF>([&](int f) {
        x[f] = *reinterpret_cast<const float2*>(in + (size_t)f * MM + m0);
    });

    // Layer 1 in f32, outputs packed immediately (f32 temps die per-pair).
    h2v h1a[9], h1b[9];                  // a = point m0, b = point m0+1
    unroll_loop<9>([&](int p) {
        float a0 = b1[2 * p], a1 = b1[2 * p + 1];
        float c0 = a0, c1 = a1;
        unroll_loop<FF>([&](int i) {
            float w0 = w1[(2 * p) * FF + i];
            float w1_ = w1[(2 * p + 1) * FF + i];
            a0 = fmaf(w0, x[i].x, a0);  c0 = fmaf(w0, x[i].y, c0);
            a1 = fmaf(w1_, x[i].x, a1); c1 = fmaf(w1_, x[i].y, c1);
        });
        h1a[p] = pkrtz(fmaxf(a0, 0.0f), fmaxf(a1, 0.0f));
        h1b[p] = pkrtz(fmaxf(c0, 0.0f), fmaxf(c1, 0.0f));
    });

    // Layer 2: each weight pair feeds both points (4 dot2 per 2 outputs).
    h2v h2a[18], h2b[18];
    unroll_loop<18>([&](int p) {
        float a0 = b2[2 * p], a1 = b2[2 * p + 1];
        float c0 = a0, c1 = a1;
        unroll_loop<9>([&](int ip) {
            h2v w0 = w2h[(2 * p) * 9 + ip];
            h2v w1_ = w2h[(2 * p + 1) * 9 + ip];
            a0 = dot2(w0, h1a[ip], a0);  c0 = dot2(w0, h1b[ip], c0);
            a1 = dot2(w1_, h1a[ip], a1); c1 = dot2(w1_, h1b[ip], c1);
        });
        h2a[p] = pkrtz(fmaxf(a0, 0.0f), fmaxf(a1, 0.0f));
        h2b[p] = pkrtz(fmaxf(c0, 0.0f), fmaxf(c1, 0.0f));
    });

    // Layer 3 fused with layer 4: h3 never materializes.
    float va = b4[0], vb = va;
    unroll_loop<36>([&](int o) {
        float a = b3[o], c = a;
        unroll_loop<18>([&](int ip) {
            h2v w = w3h[o * 18 + ip];
            a = dot2(w, h2a[ip], a);
            c = dot2(w, h2b[ip], c);
        });
        float w4o = w4[o];
        va = fmaf(w4o, fmaxf(a, 0.0f), va);
        vb = fmaf(w4o, fmaxf(c, 0.0f), vb);
    });

    int2 rr = *reinterpret_cast<const int2*>(idx + m0);        // rows r0,r1
    int2 cc = *reinterpret_cast<const int2*>(idx + MM + m0);   // cols c0,c1
    // high word = m+1 (unique, later m wins => numpy last-write-wins),
    // low word = value bits (payload only, never decides the compare)
    unsigned long long pa =
        ((unsigned long long)(unsigned)(m0 + 1) << 32) | (unsigned)__float_as_uint(va);
    unsigned long long pb =
        ((unsigned long long)(unsigned)(m0 + 2) << 32) | (unsigned)__float_as_uint(vb);
    atomicMax(&grid[rr.x * NN + cc.x], pa);
    atomicMax(&grid[rr.y * NN + cc.y], pb);
}

// ---------------- fused epilogue: rows by block, cols by atomic -------------
#define CCH 50
#define CR  (KK / CCH)   // 20 rows per col-chunk; 50x4 = 200 col blocks

__global__ __launch_bounds__(256) void maxes(const unsigned long long* __restrict__ g,
                                             float* __restrict__ out) {
    int b = blockIdx.x;
    if (b < KK) {
        // --- row max: one block per row ---
        int r = b;
        float mx = SENTINEL;
        for (int c = threadIdx.x; c < NN; c += 256) {
            unsigned long long p = g[(size_t)r * NN + c];
            if (p) mx = fmaxf(mx, __uint_as_float((unsigned)p));
        }
        __shared__ float red[256];
        red[threadIdx.x] = mx;
        __syncthreads();
        for (int s = 128; s > 0; s >>= 1) {
            if (threadIdx.x < s)
                red[threadIdx.x] = fmaxf(red[threadIdx.x], red[threadIdx.x + s]);
            __syncthreads();
        }
        if (threadIdx.x == 0) out[r] = red[0];
    } else {
        // --- col partial max over a 20-row chunk, finished via float atomicMax
        // (out[KK..KK+NN) pre-set to SENTINEL by prep; all values finite) ---
        int cb = b - KK;                       // 0..199
        int n  = (cb & 3) * 256 + (int)threadIdx.x;
        if (n < NN) {
            int k0 = (cb >> 2) * CR;
            float mx = SENTINEL;
            for (int k = k0; k < k0 + CR; ++k) {
                unsigned long long p = g[(size_t)k * NN + n];
                if (p) mx = fmaxf(mx, __uint_as_float((unsigned)p));
            }
            atomicMax(out + KK + n, mx);
        }
    }
}

extern "C" void kernel_launch(void* const* d_in, const int* in_sizes, int n_in,
                              void* d_out, int out_size, void* d_ws, size_t ws_size,
                              hipStream_t stream) {
    const float* in  = (const float*)d_in[0];
    // d_in[1] = T_out (zeros) — unused
    const int*   idx = (const int*)d_in[2];
    const float* w1  = (const float*)d_in[3];
    const float* b1  = (const float*)d_in[4];
    const float* w2  = (const float*)d_in[5];
    const float* b2  = (const float*)d_in[6];
    const float* w3  = (const float*)d_in[7];
    const float* b3  = (const float*)d_in[8];
    const float* w4  = (const float*)d_in[9];
    const float* b4  = (const float*)d_in[10];

    unsigned long long* grid = (unsigned long long*)d_ws;            // 8 MB
    // packed f16 weights right after grid (16B-aligned offsets)
    h2v* w2h = (h2v*)((char*)d_ws + 8000000);        // 324*4 = 1296 B
    h2v* w3h = (h2v*)((char*)d_ws + 8001312);        // 648*4 = 2592 B
    float* out  = (float*)d_out;

    // 3 launches total (was 6): prep | mlp_scatter | maxes
    prep<<<ZB + SB + 1, 256, 0, stream>>>((ulonglong2*)grid, out + KK, w2, w3, w2h, w3h);

    mlp_scatter<<<(MM / 2 + 255) / 256, 256, 0, stream>>>(
        in, idx, w1, b1, w2h, b2, w3h, b3, w4, b4, grid);

    maxes<<<KK + 4 * CCH, 256, 0, stream>>>(grid, out);
}

// Round 5
// 159.581 us; speedup vs baseline: 1.0306x; 1.0306x over previous
//
#include <hip/hip_runtime.h>
#include <stdint.h>

#define KK 1000
#define NN 1000
#define MM 900000
#define FF 7
#define SENTINEL -9999.0f

typedef __fp16 f16x8 __attribute__((ext_vector_type(8)));
typedef float  f32x4 __attribute__((ext_vector_type(4)));

// Compile-time unroller: indices reach bodies as constants -> SROA, no scratch.
template <int N, typename F>
__device__ __forceinline__ void unroll_loop(F&& f) {
    if constexpr (N > 0) {
        unroll_loop<N - 1>(static_cast<F&&>(f));
        f(N - 1);
    }
}

__device__ __forceinline__ unsigned pk2(float a, float b) {
    return __builtin_bit_cast(unsigned, __builtin_amdgcn_cvt_pkrtz(a, b));
}

// ---------------- prep: zero grid + col-max sentinels -----------------------
#define ZB ((KK * NN / 2 + 255) / 256)
#define SB 4

__global__ __launch_bounds__(256) void prep(ulonglong2* __restrict__ g,
                                            float* __restrict__ outcol) {
    int b = blockIdx.x;
    if (b < ZB) {
        int i = b * 256 + threadIdx.x;
        if (i < KK * NN / 2) g[i] = make_ulonglong2(0ULL, 0ULL);
    } else {
        int i = (b - ZB) * 256 + threadIdx.x;
        if (i < NN) outcol[i] = SENTINEL;
    }
}

// ---------------- MLP via MFMA + last-write-wins scatter --------------------
// R0-R4 data: kernel is bound by dynamic instruction count (~50% VALUBusy at
// every occupancy/P; I-fetch of the loop-free body caps issue). MFMA is the
// only order-of-magnitude instruction crusher: L2+L3 = 36 MFMA/wave instead
// of ~3900 dot2. Layout contracts (gfx950 16x16x32):
//   A frag: row = lane&15, k = 8*(lane>>4)+[0..8)   (one ds_read_b128)
//   B frag: col = lane&15, k = 8*(lane>>4)+[0..8)
//   D:      col = lane&15, row = 4*(lane>>4)+reg    (m89-verified)
// Activations live in per-wave LDS slabs, [point][channel] f16, 144B stride
// (16B-aligned, ~2-way banks). Wave-synchronous LDS: program order only.
#define W2_OFF  0                    // 48 rows x 80 B   (36x18 f16 + pad)
#define W3_OFF  3840                 // 48 rows x 144 B  (36x36 f16 + pad)
#define W4_OFF  10752                // 48 f32
#define B2_OFF  10944                // 48 f32
#define B3_OFF  11136                // 48 f32
#define ACT_OFF 11328                // + wave*9216 (64 pts x 144 B), 4 waves
#define LDS_BYTES (ACT_OFF + 4 * 9216)   // 48192

__global__ __launch_bounds__(256, 3) void mlp_scatter(
    const float* __restrict__ in,    // [F][M]
    const int*   __restrict__ idx,   // [2][M]
    const float* __restrict__ w1, const float* __restrict__ b1,   // 18x7, 18
    const float* __restrict__ w2, const float* __restrict__ b2,   // 36x18, 36
    const float* __restrict__ w3, const float* __restrict__ b3,   // 36x36, 36
    const float* __restrict__ w4, const float* __restrict__ b4,   // 1x36, 1
    unsigned long long* __restrict__ grid)                        // K*N packed
{
    __shared__ __align__(16) char smem[LDS_BYTES];
    const int t = threadIdx.x;

    // Zero everything once (pad channels/rows must be 0.0, and raw LDS could
    // hold NaN patterns: 0 * NaN would poison accumulators).
    for (int i = t; i < LDS_BYTES / 16; i += 256)
        ((uint4*)smem)[i] = make_uint4(0, 0, 0, 0);
    __syncthreads();

    // Stage weights: w2/w3 as f16 rows (A-side), w4/b2/b3 as f32 (exact bias).
    for (int i = t; i < 36 * 18; i += 256) {
        int r = i / 18, k = i - r * 18;
        ((__fp16*)(smem + W2_OFF + r * 80))[k] = (__fp16)w2[i];
    }
    for (int i = t; i < 36 * 36; i += 256) {
        int r = i / 36, k = i - r * 36;
        ((__fp16*)(smem + W3_OFF + r * 144))[k] = (__fp16)w3[i];
    }
    if (t < 36) {
        ((float*)(smem + W4_OFF))[t] = w4[t];
        ((float*)(smem + B2_OFF))[t] = b2[t];
        ((float*)(smem + B3_OFF))[t] = b3[t];
    }
    __syncthreads();

    const int wave = t >> 6, l = t & 63;
    const int g = l >> 4, li = l & 15;
    char* act = smem + ACT_OFF + wave * 9216;
    const int mbase = blockIdx.x * 256 + wave * 64;
    if (mbase >= MM) return;             // after both barriers: safe

    // ---- Layer 1: per-lane f32 VALU (126 fma), pack h1 -> own LDS row ----
    const int m = mbase + l;
    const int mc = m < MM ? m : MM - 1;  // clamp: garbage rows never scattered
    float x[FF];
    unroll_loop<FF>([&](int f) { x[f] = in[(size_t)f * MM + mc]; });

    unsigned hw[9];
    unroll_loop<9>([&](int p) {
        float a = b1[2 * p], b = b1[2 * p + 1];
        unroll_loop<FF>([&](int i) {
            a = fmaf(w1[(2 * p) * FF + i], x[i], a);
            b = fmaf(w1[(2 * p + 1) * FF + i], x[i], b);
        });
        hw[p] = pk2(fmaxf(a, 0.0f), fmaxf(b, 0.0f));
    });
    {
        char* row = act + l * 144;       // ch 18..31 stay zero (K-pad for L2)
        *(uint4*)(row)      = make_uint4(hw[0], hw[1], hw[2], hw[3]);
        *(uint4*)(row + 16) = make_uint4(hw[4], hw[5], hw[6], hw[7]);
        *(uint2*)(row + 32) = make_uint2(hw[8], 0u);
    }

    const f32x4 zf = {0.f, 0.f, 0.f, 0.f};

    // ---- Layer 2: h2[36ch][64pt] = relu(w2 @ h1 + b2), 12 MFMA ----
    f16x8 a2[3], bq[4];
    unroll_loop<3>([&](int T) {
        a2[T] = *(const f16x8*)(smem + W2_OFF + (16 * T + li) * 80 + g * 16);
    });
    unroll_loop<4>([&](int q) {          // all B reads BEFORE any D write
        bq[q] = *(const f16x8*)(act + (16 * q + li) * 144 + g * 16);
    });
    f32x4 b2v[3];
    unroll_loop<3>([&](int T) {
        b2v[T] = *(const f32x4*)(smem + B2_OFF + (16 * T + 4 * g) * 4);
    });
    f32x4 acc[3][4];
    unroll_loop<3>([&](int T) { unroll_loop<4>([&](int q) {
        acc[T][q] = __builtin_amdgcn_mfma_f32_16x16x32_f16(a2[T], bq[q], zf, 0, 0, 0);
    }); });
    unroll_loop<3>([&](int T) { unroll_loop<4>([&](int q) {
        f32x4 d = acc[T][q];
        unsigned lo = pk2(fmaxf(d[0] + b2v[T][0], 0.0f), fmaxf(d[1] + b2v[T][1], 0.0f));
        unsigned hi = pk2(fmaxf(d[2] + b2v[T][2], 0.0f), fmaxf(d[3] + b2v[T][3], 0.0f));
        // point 16q+li, channels 16T+4g+[0..4); ch 48..63 stay zero (K-pad)
        *(uint2*)(act + (16 * q + li) * 144 + (16 * T + 4 * g) * 2) = make_uint2(lo, hi);
    }); });

    // ---- Layer 3 + 4: 24 MFMA, then per-lane w4 partials + butterfly ----
    f16x8 a3[3][2];
    unroll_loop<3>([&](int T) { unroll_loop<2>([&](int s) {
        a3[T][s] = *(const f16x8*)(smem + W3_OFF + (16 * T + li) * 144 + s * 64 + g * 16);
    }); });
    f32x4 wv[3], b3v[3];
    unroll_loop<3>([&](int T) {
        wv[T]  = *(const f32x4*)(smem + W4_OFF + (16 * T + 4 * g) * 4);
        b3v[T] = *(const f32x4*)(smem + B3_OFF + (16 * T + 4 * g) * 4);
    });
    float vfin = 0.0f;
    unroll_loop<4>([&](int q) {
        const char* brow = act + (16 * q + li) * 144;
        f16x8 bb0 = *(const f16x8*)(brow + g * 16);
        f16x8 bb1 = *(const f16x8*)(brow + 64 + g * 16);
        float s = 0.0f;
        unroll_loop<3>([&](int T) {
            f32x4 c = __builtin_amdgcn_mfma_f32_16x16x32_f16(a3[T][0], bb0, zf, 0, 0, 0);
            c = __builtin_amdgcn_mfma_f32_16x16x32_f16(a3[T][1], bb1, c, 0, 0, 0);
            s += wv[T][0] * fmaxf(c[0] + b3v[T][0], 0.0f)
               + wv[T][1] * fmaxf(c[1] + b3v[T][1], 0.0f)
               + wv[T][2] * fmaxf(c[2] + b3v[T][2], 0.0f)
               + wv[T][3] * fmaxf(c[3] + b3v[T][3], 0.0f);
        });
        s += __shfl_xor(s, 16);          // sum the 4 lane-groups (channels)
        s += __shfl_xor(s, 32);
        if (g == q) vfin = s;            // lane keeps point 16g+li
    });

    const int mf = mbase + 16 * g + li;
    if (mf < MM) {
        float v = vfin + b4[0];
        int r = idx[mf];
        int c = idx[MM + mf];
        // high word = m+1 (unique, later m wins => numpy last-write-wins)
        unsigned long long packed =
            ((unsigned long long)(unsigned)(mf + 1) << 32) | (unsigned)__float_as_uint(v);
        atomicMax(&grid[r * NN + c], packed);
    }
}

// ---------------- fused epilogue: rows by block, cols by atomic -------------
#define CCH 50
#define CR  (KK / CCH)   // 20 rows per col-chunk

__global__ __launch_bounds__(256) void maxes(const unsigned long long* __restrict__ g,
                                             float* __restrict__ out) {
    int b = blockIdx.x;
    if (b < KK) {
        int r = b;
        float mx = SENTINEL;
        for (int c = threadIdx.x; c < NN; c += 256) {
            unsigned long long p = g[(size_t)r * NN + c];
            if (p) mx = fmaxf(mx, __uint_as_float((unsigned)p));
        }
        __shared__ float red[256];
        red[threadIdx.x] = mx;
        __syncthreads();
        for (int s = 128; s > 0; s >>= 1) {
            if (threadIdx.x < s)
                red[threadIdx.x] = fmaxf(red[threadIdx.x], red[threadIdx.x + s]);
            __syncthreads();
        }
        if (threadIdx.x == 0) out[r] = red[0];
    } else {
        int cb = b - KK;
        int n  = (cb & 3) * 256 + (int)threadIdx.x;
        if (n < NN) {
            int k0 = (cb >> 2) * CR;
            float mx = SENTINEL;
            for (int k = k0; k < k0 + CR; ++k) {
                unsigned long long p = g[(size_t)k * NN + n];
                if (p) mx = fmaxf(mx, __uint_as_float((unsigned)p));
            }
            atomicMax(out + KK + n, mx);   // out[KK..] pre-set to SENTINEL
        }
    }
}

extern "C" void kernel_launch(void* const* d_in, const int* in_sizes, int n_in,
                              void* d_out, int out_size, void* d_ws, size_t ws_size,
                              hipStream_t stream) {
    const float* in  = (const float*)d_in[0];
    // d_in[1] = T_out (zeros) — unused
    const int*   idx = (const int*)d_in[2];
    const float* w1  = (const float*)d_in[3];
    const float* b1  = (const float*)d_in[4];
    const float* w2  = (const float*)d_in[5];
    const float* b2  = (const float*)d_in[6];
    const float* w3  = (const float*)d_in[7];
    const float* b3  = (const float*)d_in[8];
    const float* w4  = (const float*)d_in[9];
    const float* b4  = (const float*)d_in[10];

    unsigned long long* grid = (unsigned long long*)d_ws;   // 8 MB
    float* out = (float*)d_out;

    prep<<<ZB + SB, 256, 0, stream>>>((ulonglong2*)grid, out + KK);

    mlp_scatter<<<(MM + 255) / 256, 256, 0, stream>>>(
        in, idx, w1, b1, w2, b2, w3, b3, w4, b4, grid);

    maxes<<<KK + 4 * CCH, 256, 0, stream>>>(grid, out);
}

// Round 6
// 151.878 us; speedup vs baseline: 1.0829x; 1.0507x over previous
//
#include <hip/hip_runtime.h>
#include <stdint.h>

#define KK 1000
#define NN 1000
#define MM 900000
#define FF 7
#define SENTINEL -9999.0f

typedef __fp16 f16x8 __attribute__((ext_vector_type(8)));
typedef float  f32x4 __attribute__((ext_vector_type(4)));

// Compile-time unroller: indices reach bodies as constants -> SROA, no scratch.
template <int N, typename F>
__device__ __forceinline__ void unroll_loop(F&& f) {
    if constexpr (N > 0) {
        unroll_loop<N - 1>(static_cast<F&&>(f));
        f(N - 1);
    }
}

__device__ __forceinline__ unsigned pk2(float a, float b) {
    return __builtin_bit_cast(unsigned, __builtin_amdgcn_cvt_pkrtz(a, b));
}

// ---------------- prep: zero grid + col-max sentinels -----------------------
#define ZB ((KK * NN / 2 + 255) / 256)
#define SB 4

__global__ __launch_bounds__(256) void prep(ulonglong2* __restrict__ g,
                                            float* __restrict__ outcol) {
    int b = blockIdx.x;
    if (b < ZB) {
        int i = b * 256 + threadIdx.x;
        if (i < KK * NN / 2) g[i] = make_ulonglong2(0ULL, 0ULL);
    } else {
        int i = (b - ZB) * 256 + threadIdx.x;
        if (i < NN) outcol[i] = SENTINEL;
    }
}

// ---------------- persistent MFMA MLP + scatter -----------------------------
// R5 post-mortem: 85% idle at 25% occupancy; 3 implementations stuck at
// ~55us => latency-bound on per-block phase chains, not issue-bound.
// This version: persistent blocks (prologue amortized, steady loop has NO
// barriers), LDS cut to 40448B -> 4 blocks/CU (16 waves), h2 chunked per
// 16-point q-group. Fragment layouts identical to R5 (absmax-verified).
//   A frag: row = lane&15 (+16T), k = 8*(lane>>4)+[0..8)
//   B frag: col = lane&15, k = 8*(lane>>4)+[0..8)
//   D:      col = lane&15, row = 4*(lane>>4)+reg (+16T)
// Strides: h1/W2 rows 80B (bank: li*20%32, conflict-free), h2/W3 rows 144B
// (li*36%32 = 2-way, free per m136); all 16B-aligned for ds_*_b128.
#define W2_OFF   0                    // 48 rows x 80 B  (36x18 f16, pads 0)
#define W3_OFF   3840                 // 48 rows x 144 B (36x36 f16, pads 0)
#define WGT_BYTES 10752
#define H2_OFF   5120                 // within a wave slab: h1 64x80, h2 16x144
#define WAVE_ACT 7424
#define LDS_BYTES (WGT_BYTES + 4 * WAVE_ACT)   // 40448 -> 4 blocks/CU
#define GRID_BLKS 1024                // 4 per CU, all resident

__global__ __launch_bounds__(256, 4) void mlp_scatter(
    const float* __restrict__ in,    // [F][M]
    const int*   __restrict__ idx,   // [2][M]
    const float* __restrict__ w1, const float* __restrict__ b1,   // 18x7, 18
    const float* __restrict__ w2, const float* __restrict__ b2,   // 36x18, 36
    const float* __restrict__ w3, const float* __restrict__ b3,   // 36x36, 36
    const float* __restrict__ w4, const float* __restrict__ b4,   // 1x36, 1
    unsigned long long* __restrict__ grid)                        // K*N packed
{
    __shared__ __align__(16) char smem[LDS_BYTES];
    const int t = threadIdx.x;
    const int wave = t >> 6, l = t & 63;
    const int g = l >> 4, li = l & 15;
    char* hs1 = smem + WGT_BYTES + wave * WAVE_ACT;   // h1: [64 pt][80 B]
    char* hs2 = hs1 + H2_OFF;                         // h2: [16 pt][144 B]

    // ---- prologue (once per block): zero weights region + act pads ----
    for (int i = t; i < WGT_BYTES / 16; i += 256)
        ((uint4*)smem)[i] = make_uint4(0, 0, 0, 0);
    {   // h1 row pads: bytes 40..79 (ch 20..31 K-pad + bank pad); tiles
        // rewrite only bytes 0..39, so these stay zero for every tile.
        char* row = hs1 + l * 80;
        *(uint2*)(row + 40) = make_uint2(0, 0);
        *(uint4*)(row + 48) = make_uint4(0, 0, 0, 0);
        *(uint4*)(row + 64) = make_uint4(0, 0, 0, 0);
    }
    if (l < 16) {  // h2 row pads: bytes 96..143 (ch 48..63 K-pad + bank pad)
        char* row = hs2 + l * 144;
        *(uint4*)(row + 96)  = make_uint4(0, 0, 0, 0);
        *(uint4*)(row + 112) = make_uint4(0, 0, 0, 0);
        *(uint4*)(row + 128) = make_uint4(0, 0, 0, 0);
    }
    __syncthreads();
    for (int i = t; i < 36 * 18; i += 256) {          // w2 -> f16 rows
        int r = i / 18, k = i - r * 18;
        ((__fp16*)(smem + W2_OFF + r * 80))[k] = (__fp16)w2[i];
    }
    for (int i = t; i < 36 * 36; i += 256) {          // w3 -> f16 rows
        int r = i / 36, k = i - r * 36;
        ((__fp16*)(smem + W3_OFF + r * 144))[k] = (__fp16)w3[i];
    }
    __syncthreads();

    // ---- per-wave held fragments (loaded once) ----
    const f32x4 zf = {0.f, 0.f, 0.f, 0.f};
    f16x8 a2[3], a3[3][2];
    f32x4 b2v[3], b3v[3], wv[3];
    unroll_loop<3>([&](int T) {
        a2[T]    = *(const f16x8*)(smem + W2_OFF + (16 * T + li) * 80 + g * 16);
        a3[T][0] = *(const f16x8*)(smem + W3_OFF + (16 * T + li) * 144 + g * 16);
        a3[T][1] = *(const f16x8*)(smem + W3_OFF + (16 * T + li) * 144 + 64 + g * 16);
        int r0 = 16 * T + 4 * g;       // bias/w4 rows: pad rows (>=36) read 0
        b2v[T] = r0 < 36 ? *(const f32x4*)(b2 + r0) : zf;
        b3v[T] = r0 < 36 ? *(const f32x4*)(b3 + r0) : zf;
        wv[T]  = r0 < 36 ? *(const f32x4*)(w4 + r0) : zf;
    });
    const float fb4 = b4[0];

    // ---- steady-state tile loop: NO barriers (act slabs are per-wave) ----
    for (int tile = blockIdx.x; tile * 256 < MM; tile += GRID_BLKS) {
        const int mbase = tile * 256 + wave * 64;
        const int m  = mbase + l;
        const int mc = m < MM ? m : MM - 1;   // clamped lanes never scattered

        // Layer 1: per-lane f32 (126 fma), pack to own h1 row
        float x[FF];
        unroll_loop<FF>([&](int f) { x[f] = in[(size_t)f * MM + mc]; });
        unsigned hw[9];
        unroll_loop<9>([&](int p) {
            float a = b1[2 * p], b = b1[2 * p + 1];
            unroll_loop<FF>([&](int i) {
                a = fmaf(w1[(2 * p) * FF + i], x[i], a);
                b = fmaf(w1[(2 * p + 1) * FF + i], x[i], b);
            });
            hw[p] = pk2(fmaxf(a, 0.0f), fmaxf(b, 0.0f));
        });
        {
            char* row = hs1 + l * 80;
            *(uint4*)(row)      = make_uint4(hw[0], hw[1], hw[2], hw[3]);
            *(uint4*)(row + 16) = make_uint4(hw[4], hw[5], hw[6], hw[7]);
            *(uint2*)(row + 32) = make_uint2(hw[8], 0u);  // ch 18,19 = 0
        }

        // Layers 2+3+4 per 16-point q-group (h2 slab reused each q)
        float vfin = 0.0f;
        unroll_loop<4>([&](int q) {
            f16x8 bq = *(const f16x8*)(hs1 + (16 * q + li) * 80 + g * 16);
            f32x4 acc[3];
            unroll_loop<3>([&](int T) {
                acc[T] = __builtin_amdgcn_mfma_f32_16x16x32_f16(a2[T], bq, zf, 0, 0, 0);
            });
            unroll_loop<3>([&](int T) {   // bias+relu+pack -> h2 row li
                unsigned lo = pk2(fmaxf(acc[T][0] + b2v[T][0], 0.0f),
                                  fmaxf(acc[T][1] + b2v[T][1], 0.0f));
                unsigned hi = pk2(fmaxf(acc[T][2] + b2v[T][2], 0.0f),
                                  fmaxf(acc[T][3] + b2v[T][3], 0.0f));
                *(uint2*)(hs2 + li * 144 + (16 * T + 4 * g) * 2) = make_uint2(lo, hi);
            });
            f16x8 bb0 = *(const f16x8*)(hs2 + li * 144 + g * 16);
            f16x8 bb1 = *(const f16x8*)(hs2 + li * 144 + 64 + g * 16);
            float s = 0.0f;
            unroll_loop<3>([&](int T) {
                f32x4 c = __builtin_amdgcn_mfma_f32_16x16x32_f16(a3[T][0], bb0, zf, 0, 0, 0);
                c = __builtin_amdgcn_mfma_f32_16x16x32_f16(a3[T][1], bb1, c, 0, 0, 0);
                s += wv[T][0] * fmaxf(c[0] + b3v[T][0], 0.0f)
                   + wv[T][1] * fmaxf(c[1] + b3v[T][1], 0.0f)
                   + wv[T][2] * fmaxf(c[2] + b3v[T][2], 0.0f)
                   + wv[T][3] * fmaxf(c[3] + b3v[T][3], 0.0f);
            });
            s += __shfl_xor(s, 16);       // sum channel groups (4 g-slices)
            s += __shfl_xor(s, 32);
            if (g == q) vfin = s;         // lane keeps point 16g+li
        });

        const int mf = mbase + 16 * g + li;
        if (mf < MM) {
            float v = vfin + fb4;
            int r = idx[mf];
            int c = idx[MM + mf];
            // high word = m+1: unique, later m wins => numpy last-write-wins
            unsigned long long packed =
                ((unsigned long long)(unsigned)(mf + 1) << 32) |
                (unsigned)__float_as_uint(v);
            atomicMax(&grid[r * NN + c], packed);
        }
    }
}

// ---------------- fused epilogue: rows by block, cols by atomic -------------
#define CCH 50
#define CR  (KK / CCH)   // 20 rows per col-chunk

__global__ __launch_bounds__(256) void maxes(const unsigned long long* __restrict__ g,
                                             float* __restrict__ out) {
    int b = blockIdx.x;
    if (b < KK) {
        int r = b;
        float mx = SENTINEL;
        for (int c = threadIdx.x; c < NN; c += 256) {
            unsigned long long p = g[(size_t)r * NN + c];
            if (p) mx = fmaxf(mx, __uint_as_float((unsigned)p));
        }
        __shared__ float red[256];
        red[threadIdx.x] = mx;
        __syncthreads();
        for (int s = 128; s > 0; s >>= 1) {
            if (threadIdx.x < s)
                red[threadIdx.x] = fmaxf(red[threadIdx.x], red[threadIdx.x + s]);
            __syncthreads();
        }
        if (threadIdx.x == 0) out[r] = red[0];
    } else {
        int cb = b - KK;
        int n  = (cb & 3) * 256 + (int)threadIdx.x;
        if (n < NN) {
            int k0 = (cb >> 2) * CR;
            float mx = SENTINEL;
            for (int k = k0; k < k0 + CR; ++k) {
                unsigned long long p = g[(size_t)k * NN + n];
                if (p) mx = fmaxf(mx, __uint_as_float((unsigned)p));
            }
            atomicMax(out + KK + n, mx);   // out[KK..] pre-set to SENTINEL
        }
    }
}

extern "C" void kernel_launch(void* const* d_in, const int* in_sizes, int n_in,
                              void* d_out, int out_size, void* d_ws, size_t ws_size,
                              hipStream_t stream) {
    const float* in  = (const float*)d_in[0];
    // d_in[1] = T_out (zeros) — unused
    const int*   idx = (const int*)d_in[2];
    const float* w1  = (const float*)d_in[3];
    const float* b1  = (const float*)d_in[4];
    const float* w2  = (const float*)d_in[5];
    const float* b2  = (const float*)d_in[6];
    const float* w3  = (const float*)d_in[7];
    const float* b3  = (const float*)d_in[8];
    const float* w4  = (const float*)d_in[9];
    const float* b4  = (const float*)d_in[10];

    unsigned long long* grid = (unsigned long long*)d_ws;   // 8 MB
    float* out = (float*)d_out;

    prep<<<ZB + SB, 256, 0, stream>>>((ulonglong2*)grid, out + KK);

    mlp_scatter<<<GRID_BLKS, 256, 0, stream>>>(
        in, idx, w1, b1, w2, b2, w3, b3, w4, b4, grid);

    maxes<<<KK + 4 * CCH, 256, 0, stream>>>(grid, out);
}